// Round 1
// baseline (1048.263 us; speedup 1.0000x reference)
//
#include <hip/hip_runtime.h>

// GraphSAGE 2-layer, mean aggregation, fp32.
// N=100000 nodes, E=2*800000 edges, feat 64 -> 64 (relu) -> 32.
//
// Phases:
//   1. memset deg/s1/s2 regions of ws
//   2. scatter1: s1[dst] += x[src] (64 f32 atomics/edge), deg[dst] += 1
//   3. linear1:  h = relu((s1/deg) @ W1l^T + b1 + x @ W1r^T)
//   4. scatter2: s2[dst] += h[src]
//   5. linear2:  out = (s2/deg) @ W2l^T + b2 + h @ W2r^T

constexpr int N_NODES = 100000;
constexpr int E_HALF  = 800000;

// ---------------- scatter: 64 threads (one wave) per edge ----------------
__global__ __launch_bounds__(256) void scatter_add_kernel(
    const float* __restrict__ feat,   // [N,64]
    const int*   __restrict__ ei1,    // [2,E_HALF]
    const int*   __restrict__ ei2,    // [2,E_HALF]
    float*       __restrict__ s,      // [N,64] accumulator (pre-zeroed)
    float*       __restrict__ deg,    // [N] (pre-zeroed)
    int do_deg)
{
    long long tid = (long long)blockIdx.x * 256 + threadIdx.x;
    long long e   = tid >> 6;          // edge id
    int       f   = (int)(tid & 63);   // feature lane
    if (e >= 2LL * E_HALF) return;
    int src, dst;
    if (e < E_HALF) {
        int ee = (int)e;
        src = ei1[ee];
        dst = ei1[E_HALF + ee];
    } else {
        int ee = (int)(e - E_HALF);
        src = ei2[ee];
        dst = ei2[E_HALF + ee];
    }
    float v = feat[src * 64 + f];                 // coalesced 256B per wave
    atomicAdd(&s[dst * 64 + f], v);               // coalesced 256B per wave
    if (do_deg && f == 0) atomicAdd(&deg[dst], 1.0f);
}

// ---------------- fused linear: out = (s/deg)@Wl^T + b + x@Wr^T ----------
// OUT in {64,32}. TPN = OUT/4 threads per node (4 outputs each, float4),
// NPB = 256/TPN nodes per block. W staged transposed in LDS (o contiguous).
template <int OUT, int RELU>
__global__ __launch_bounds__(256) void sage_linear_kernel(
    const float* __restrict__ s,     // [N,64] aggregated sums
    const float* __restrict__ xin,   // [N,64] self features
    const float* __restrict__ deg,   // [N]
    const float* __restrict__ Wl,    // [OUT,64] row-major
    const float* __restrict__ bias,  // [OUT]
    const float* __restrict__ Wr,    // [OUT,64]
    float*       __restrict__ out)   // [N,OUT]
{
    constexpr int TPN = OUT / 4;     // threads per node
    constexpr int NPB = 256 / TPN;   // nodes per block

    __shared__ __align__(16) float wlT[64 * OUT];   // [f][o]
    __shared__ __align__(16) float wrT[64 * OUT];   // [f][o]
    __shared__ float xr[NPB * 65];                  // padded node rows
    __shared__ float mr[NPB * 65];

    int tid = threadIdx.x;

    // Stage weights transposed: wT[f*OUT + o] = W[o*64 + f]. Coalesced global.
    for (int i = tid; i < OUT * 64; i += 256) {
        int o = i >> 6, f = i & 63;
        wlT[f * OUT + o] = Wl[i];
        wrT[f * OUT + o] = Wr[i];
    }

    int node0 = blockIdx.x * NPB;
    // Stage x rows and mean rows (s * 1/deg). Coalesced global.
    for (int i = tid; i < NPB * 64; i += 256) {
        int n = i >> 6, f = i & 63;
        int g = node0 + n;
        float rd = 1.0f / fmaxf(deg[g], 1.0f);
        xr[n * 65 + f] = xin[g * 64 + f];
        mr[n * 65 + f] = s[g * 64 + f] * rd;
    }
    __syncthreads();

    int n  = tid / TPN;
    int o0 = (tid % TPN) * 4;

    float a0 = bias[o0], a1 = bias[o0 + 1], a2 = bias[o0 + 2], a3 = bias[o0 + 3];
    #pragma unroll
    for (int f = 0; f < 64; f++) {
        float xv = xr[n * 65 + f];   // LDS broadcast (distinct banks via pad)
        float mv = mr[n * 65 + f];
        const float4 wl4 = *reinterpret_cast<const float4*>(&wlT[f * OUT + o0]);
        const float4 wr4 = *reinterpret_cast<const float4*>(&wrT[f * OUT + o0]);
        a0 += mv * wl4.x + xv * wr4.x;
        a1 += mv * wl4.y + xv * wr4.y;
        a2 += mv * wl4.z + xv * wr4.z;
        a3 += mv * wl4.w + xv * wr4.w;
    }
    if (RELU) {
        a0 = fmaxf(a0, 0.0f); a1 = fmaxf(a1, 0.0f);
        a2 = fmaxf(a2, 0.0f); a3 = fmaxf(a3, 0.0f);
    }
    float4 r = make_float4(a0, a1, a2, a3);
    *reinterpret_cast<float4*>(&out[(long long)(node0 + n) * OUT + o0]) = r;
}

extern "C" void kernel_launch(void* const* d_in, const int* in_sizes, int n_in,
                              void* d_out, int out_size, void* d_ws, size_t ws_size,
                              hipStream_t stream) {
    const float* x   = (const float*)d_in[0];
    const int*   ei1 = (const int*)d_in[1];
    const int*   ei2 = (const int*)d_in[3];
    const float* W1l = (const float*)d_in[5];
    const float* b1  = (const float*)d_in[6];
    const float* W1r = (const float*)d_in[7];
    const float* W2l = (const float*)d_in[8];
    const float* b2  = (const float*)d_in[9];
    const float* W2r = (const float*)d_in[10];
    float* out = (float*)d_out;

    // workspace layout (256B-aligned regions)
    const size_t deg_bytes = (size_t)N_NODES * 4;                  // 400000
    const size_t s_bytes   = (size_t)N_NODES * 64 * 4;             // 25.6 MB
    const size_t off_deg = 0;
    const size_t off_s1  = (deg_bytes + 255) & ~(size_t)255;       // 400128
    const size_t off_h   = off_s1 + s_bytes;
    const size_t off_s2  = off_h + s_bytes;

    char* ws = (char*)d_ws;
    float* deg = (float*)(ws + off_deg);
    float* s1  = (float*)(ws + off_s1);
    float* h   = (float*)(ws + off_h);
    float* s2  = (float*)(ws + off_s2);

    // zero deg+s1 (contiguous span) and s2; h is fully overwritten
    hipMemsetAsync(ws + off_deg, 0, off_s1 + s_bytes, stream);
    hipMemsetAsync(ws + off_s2, 0, s_bytes, stream);

    // scatter layer 1 (+ degree)
    {
        long long total = 2LL * E_HALF * 64;
        int blocks = (int)((total + 255) / 256);   // 400000
        scatter_add_kernel<<<blocks, 256, 0, stream>>>(x, ei1, ei2, s1, deg, 1);
    }
    // linear layer 1 (relu)
    sage_linear_kernel<64, 1><<<N_NODES / 16, 256, 0, stream>>>(
        s1, x, deg, W1l, b1, W1r, h);
    // scatter layer 2
    {
        long long total = 2LL * E_HALF * 64;
        int blocks = (int)((total + 255) / 256);
        scatter_add_kernel<<<blocks, 256, 0, stream>>>(h, ei1, ei2, s2, deg, 0);
    }
    // linear layer 2 (no relu), OUT=32
    sage_linear_kernel<32, 0><<<N_NODES / 32, 256, 0, stream>>>(
        s2, h, deg, W2l, b2, W2r, out);
}

// Round 2
// 509.991 us; speedup vs baseline: 2.0555x; 2.0555x over previous
//
#include <hip/hip_runtime.h>

// GraphSAGE 2-layer, mean aggregation, fp32 — gather formulation.
// N=100000 nodes, E=2*800000 edges, feat 64 -> 64 (relu) -> 32.
//
// R1 evidence: scatter atomics write through to fabric (450 MB/dispatch,
// 243G atomics/s ceiling). Fix: build per-dst bucket lists ONCE (shared by
// both layers), aggregate by gather (no atomics). CAP=64 slots/node; true
// degree max ~42 (Poisson(16) over 100K nodes); exact overflow fallback
// list keeps correctness unconditional.

constexpr int N_NODES = 100000;
constexpr int E_HALF  = 800000;
constexpr int CAP     = 64;      // slots per node
constexpr int OVF_CAP = 4096;    // overflow edge capacity (expected use: 0)

// ------------- bucket fill: one thread per edge ---------------------------
__global__ __launch_bounds__(256) void fill_kernel(
    const int* __restrict__ ei1, const int* __restrict__ ei2,
    int* __restrict__ cnt, int* __restrict__ slots,
    int* __restrict__ ovf_cnt, int* __restrict__ ovf)
{
    int e = blockIdx.x * 256 + threadIdx.x;
    if (e >= 2 * E_HALF) return;
    int src, dst;
    if (e < E_HALF) { src = ei1[e];  dst = ei1[E_HALF + e]; }
    else { int ee = e - E_HALF; src = ei2[ee]; dst = ei2[E_HALF + ee]; }
    int pos = atomicAdd(&cnt[dst], 1);
    if (pos < CAP) {
        slots[dst * CAP + pos] = src;
    } else {
        int o = atomicAdd(ovf_cnt, 1);
        if (o < OVF_CAP) { ovf[2 * o] = src; ovf[2 * o + 1] = dst; }
    }
}

// ------------- gather-mean: one wave per node, lane = feature -------------
__global__ __launch_bounds__(256) void gather_mean_kernel(
    const float* __restrict__ feat,   // [N,64]
    const int*   __restrict__ cnt,    // [N]
    const int*   __restrict__ slots,  // [N,CAP]
    float*       __restrict__ m)      // [N,64] mean output
{
    int node = blockIdx.x * 4 + (threadIdx.x >> 6);
    int f    = threadIdx.x & 63;
    if (node >= N_NODES) return;
    int c  = cnt[node];
    int cc = c < CAP ? c : CAP;
    // one coalesced 256B read covers the whole slot list (CAP==64==wave)
    int slotv = slots[node * CAP + f];
    float a0 = 0.f, a1 = 0.f, a2 = 0.f, a3 = 0.f;
    int i = 0;
    for (; i + 4 <= cc; i += 4) {      // 4 independent loads in flight
        int s0 = __shfl(slotv, i),     s1 = __shfl(slotv, i + 1);
        int s2 = __shfl(slotv, i + 2), s3 = __shfl(slotv, i + 3);
        a0 += feat[s0 * 64 + f];
        a1 += feat[s1 * 64 + f];
        a2 += feat[s2 * 64 + f];
        a3 += feat[s3 * 64 + f];
    }
    for (; i < cc; i++) a0 += feat[__shfl(slotv, i) * 64 + f];
    float rd = 1.0f / fmaxf((float)c, 1.0f);
    m[node * 64 + f] = (a0 + a1 + a2 + a3) * rd;
}

// ------------- overflow fallback (expected 0 iterations) ------------------
__global__ __launch_bounds__(256) void ovf_apply_kernel(
    const float* __restrict__ feat, const int* __restrict__ cnt,
    const int* __restrict__ ovf_cnt, const int* __restrict__ ovf,
    float* __restrict__ m)
{
    int n = *ovf_cnt;
    if (n > OVF_CAP) n = OVF_CAP;
    int total = n * 64;
    for (int t = blockIdx.x * 256 + threadIdx.x; t < total; t += gridDim.x * 256) {
        int o = t >> 6, f = t & 63;
        int src = ovf[2 * o], dst = ovf[2 * o + 1];
        float rd = 1.0f / fmaxf((float)cnt[dst], 1.0f);
        atomicAdd(&m[dst * 64 + f], feat[src * 64 + f] * rd);
    }
}

// ------------- fused linear: out = m@Wl^T + b + x@Wr^T --------------------
template <int OUT, int RELU>
__global__ __launch_bounds__(256) void sage_linear_kernel(
    const float* __restrict__ m,     // [N,64] aggregated means
    const float* __restrict__ xin,   // [N,64] self features
    const float* __restrict__ Wl,    // [OUT,64] row-major
    const float* __restrict__ bias,  // [OUT]
    const float* __restrict__ Wr,    // [OUT,64]
    float*       __restrict__ out)   // [N,OUT]
{
    constexpr int TPN = OUT / 4;     // threads per node
    constexpr int NPB = 256 / TPN;   // nodes per block

    __shared__ __align__(16) float wlT[64 * OUT];   // [f][o]
    __shared__ __align__(16) float wrT[64 * OUT];   // [f][o]
    __shared__ float xr[NPB * 65];                  // padded node rows
    __shared__ float mr[NPB * 65];

    int tid = threadIdx.x;
    for (int i = tid; i < OUT * 64; i += 256) {
        int o = i >> 6, f = i & 63;
        wlT[f * OUT + o] = Wl[i];
        wrT[f * OUT + o] = Wr[i];
    }
    int node0 = blockIdx.x * NPB;
    for (int i = tid; i < NPB * 64; i += 256) {
        int n = i >> 6, f = i & 63;
        int g = node0 + n;
        xr[n * 65 + f] = xin[g * 64 + f];
        mr[n * 65 + f] = m[g * 64 + f];
    }
    __syncthreads();

    int n  = tid / TPN;
    int o0 = (tid % TPN) * 4;

    float a0 = bias[o0], a1 = bias[o0 + 1], a2 = bias[o0 + 2], a3 = bias[o0 + 3];
    #pragma unroll
    for (int f = 0; f < 64; f++) {
        float xv = xr[n * 65 + f];
        float mv = mr[n * 65 + f];
        const float4 wl4 = *reinterpret_cast<const float4*>(&wlT[f * OUT + o0]);
        const float4 wr4 = *reinterpret_cast<const float4*>(&wrT[f * OUT + o0]);
        a0 += mv * wl4.x + xv * wr4.x;
        a1 += mv * wl4.y + xv * wr4.y;
        a2 += mv * wl4.z + xv * wr4.z;
        a3 += mv * wl4.w + xv * wr4.w;
    }
    if (RELU) {
        a0 = fmaxf(a0, 0.0f); a1 = fmaxf(a1, 0.0f);
        a2 = fmaxf(a2, 0.0f); a3 = fmaxf(a3, 0.0f);
    }
    *reinterpret_cast<float4*>(&out[(long long)(node0 + n) * OUT + o0]) =
        make_float4(a0, a1, a2, a3);
}

extern "C" void kernel_launch(void* const* d_in, const int* in_sizes, int n_in,
                              void* d_out, int out_size, void* d_ws, size_t ws_size,
                              hipStream_t stream) {
    const float* x   = (const float*)d_in[0];
    const int*   ei1 = (const int*)d_in[1];
    const int*   ei2 = (const int*)d_in[3];
    const float* W1l = (const float*)d_in[5];
    const float* b1  = (const float*)d_in[6];
    const float* W1r = (const float*)d_in[7];
    const float* W2l = (const float*)d_in[8];
    const float* b2  = (const float*)d_in[9];
    const float* W2r = (const float*)d_in[10];
    float* out = (float*)d_out;

    // workspace layout (256B-aligned)
    const size_t off_cnt    = 0;                        // int[N]      400000 B
    const size_t off_ovfcnt = 400128;                   // int
    const size_t off_ovf    = 400384;                   // int[2*OVF_CAP] 32768 B
    const size_t off_slots  = 433152;                   // int[N*CAP]  25.6 MB
    const size_t off_m      = off_slots + (size_t)N_NODES * CAP * 4;
    const size_t off_h      = off_m + (size_t)N_NODES * 64 * 4;

    char* ws = (char*)d_ws;
    int*   cnt     = (int*)(ws + off_cnt);
    int*   ovf_cnt = (int*)(ws + off_ovfcnt);
    int*   ovf     = (int*)(ws + off_ovf);
    int*   slots   = (int*)(ws + off_slots);
    float* m       = (float*)(ws + off_m);
    float* h       = (float*)(ws + off_h);

    // zero cnt + ovf_cnt (+ovf header region): 433 KB only
    hipMemsetAsync(ws, 0, off_slots, stream);

    // build bucket lists (shared by both layers)
    fill_kernel<<<(2 * E_HALF + 255) / 256, 256, 0, stream>>>(
        ei1, ei2, cnt, slots, ovf_cnt, ovf);

    // layer 1: gather-mean(x) -> m ; linear -> h (relu)
    gather_mean_kernel<<<N_NODES / 4, 256, 0, stream>>>(x, cnt, slots, m);
    ovf_apply_kernel<<<16, 256, 0, stream>>>(x, cnt, ovf_cnt, ovf, m);
    sage_linear_kernel<64, 1><<<N_NODES / 16, 256, 0, stream>>>(
        m, x, W1l, b1, W1r, h);

    // layer 2: gather-mean(h) -> m ; linear -> out
    gather_mean_kernel<<<N_NODES / 4, 256, 0, stream>>>(h, cnt, slots, m);
    ovf_apply_kernel<<<16, 256, 0, stream>>>(h, cnt, ovf_cnt, ovf, m);
    sage_linear_kernel<32, 0><<<N_NODES / 32, 256, 0, stream>>>(
        m, h, W2l, b2, W2r, out);
}

// Round 3
// 380.411 us; speedup vs baseline: 2.7556x; 1.3406x over previous
//
#include <hip/hip_runtime.h>

// GraphSAGE 2-layer, mean aggregation, fp32 — gather + split-bf16 MFMA GEMM.
// N=100000, E=1.6M, feat 64 -> 64 (relu) -> 32.
//
// R2 evidence: sage_linear was LDS-bound (4.96e7 bank-conflict cycles from
// the weight-transpose staging; inner loop structurally LDS-pipe-limited).
// Fix: linears become [N,128]@[128,OUT] GEMMs via mfma_f32_16x16x32_bf16
// with hi/lo bf16 split (3 MFMA passes ~ fp32 precision). Fragments are
// K-contiguous per lane -> load straight from global, no LDS at all.

constexpr int N_NODES = 100000;
constexpr int E_HALF  = 800000;
constexpr int CAP     = 64;
constexpr int OVF_CAP = 4096;

typedef short  s16x8 __attribute__((ext_vector_type(8)));
typedef float  f32x4 __attribute__((ext_vector_type(4)));

// ------------- bucket fill: one thread per edge ---------------------------
__global__ __launch_bounds__(256) void fill_kernel(
    const int* __restrict__ ei1, const int* __restrict__ ei2,
    int* __restrict__ cnt, int* __restrict__ slots,
    int* __restrict__ ovf_cnt, int* __restrict__ ovf)
{
    int e = blockIdx.x * 256 + threadIdx.x;
    if (e >= 2 * E_HALF) return;
    int src, dst;
    if (e < E_HALF) { src = ei1[e];  dst = ei1[E_HALF + e]; }
    else { int ee = e - E_HALF; src = ei2[ee]; dst = ei2[E_HALF + ee]; }
    int pos = atomicAdd(&cnt[dst], 1);
    if (pos < CAP) {
        slots[dst * CAP + pos] = src;
    } else {
        int o = atomicAdd(ovf_cnt, 1);
        if (o < OVF_CAP) { ovf[2 * o] = src; ovf[2 * o + 1] = dst; }
    }
}

// ------------- gather-mean: one wave per node, lane = feature -------------
__global__ __launch_bounds__(256) void gather_mean_kernel(
    const float* __restrict__ feat,   // [N,64]
    const int*   __restrict__ cnt,    // [N]
    const int*   __restrict__ slots,  // [N,CAP]
    float*       __restrict__ m)      // [N,64] mean output
{
    int node = blockIdx.x * 4 + (threadIdx.x >> 6);
    int f    = threadIdx.x & 63;
    if (node >= N_NODES) return;
    int c  = cnt[node];
    int cc = c < CAP ? c : CAP;
    int slotv = slots[node * CAP + f];
    float a0 = 0.f, a1 = 0.f, a2 = 0.f, a3 = 0.f;
    int i = 0;
    for (; i + 4 <= cc; i += 4) {
        int s0 = __shfl(slotv, i),     s1 = __shfl(slotv, i + 1);
        int s2 = __shfl(slotv, i + 2), s3 = __shfl(slotv, i + 3);
        a0 += feat[s0 * 64 + f];
        a1 += feat[s1 * 64 + f];
        a2 += feat[s2 * 64 + f];
        a3 += feat[s3 * 64 + f];
    }
    for (; i < cc; i++) a0 += feat[__shfl(slotv, i) * 64 + f];
    float rd = 1.0f / fmaxf((float)c, 1.0f);
    m[node * 64 + f] = (a0 + a1 + a2 + a3) * rd;
}

// ------------- overflow fallback (expected 0 iterations) ------------------
__global__ __launch_bounds__(256) void ovf_apply_kernel(
    const float* __restrict__ feat, const int* __restrict__ cnt,
    const int* __restrict__ ovf_cnt, const int* __restrict__ ovf,
    float* __restrict__ m)
{
    int n = *ovf_cnt;
    if (n > OVF_CAP) n = OVF_CAP;
    int total = n * 64;
    for (int t = blockIdx.x * 256 + threadIdx.x; t < total; t += gridDim.x * 256) {
        int o = t >> 6, f = t & 63;
        int src = ovf[2 * o], dst = ovf[2 * o + 1];
        float rd = 1.0f / fmaxf((float)cnt[dst], 1.0f);
        atomicAdd(&m[dst * 64 + f], feat[src * 64 + f] * rd);
    }
}

// ------------- hi/lo truncate-split of 8 floats to bf16 frags -------------
__device__ inline void split8(float4 v0, float4 v1, s16x8& hi, s16x8& lo) {
    float vs[8] = {v0.x, v0.y, v0.z, v0.w, v1.x, v1.y, v1.z, v1.w};
    s16x8 h, l;
    #pragma unroll
    for (int j = 0; j < 8; j++) {
        unsigned b  = __float_as_uint(vs[j]);
        float    hf = __uint_as_float(b & 0xFFFF0000u);
        float    r  = vs[j] - hf;            // exact
        h[j] = (short)(b >> 16);
        l[j] = (short)(__float_as_uint(r) >> 16);
    }
    hi = h; lo = l;
}

// ------------- weight prep: Wcat=[Wl|Wr] split to hi/lo bf16 [OUT,128] ----
__global__ __launch_bounds__(256) void wsplit_kernel(
    const float* __restrict__ W1l, const float* __restrict__ W1r,
    const float* __restrict__ W2l, const float* __restrict__ W2r,
    short* __restrict__ B1hi, short* __restrict__ B1lo,
    short* __restrict__ B2hi, short* __restrict__ B2lo)
{
    int i = blockIdx.x * 256 + threadIdx.x;
    float v; short* ph; short* pl; int idx;
    if (i < 64 * 128) {
        int o = i >> 7, k = i & 127;
        v = (k < 64) ? W1l[o * 64 + k] : W1r[o * 64 + (k - 64)];
        ph = B1hi; pl = B1lo; idx = i;
    } else if (i < 64 * 128 + 32 * 128) {
        int j = i - 64 * 128;
        int o = j >> 7, k = j & 127;
        v = (k < 64) ? W2l[o * 64 + k] : W2r[o * 64 + (k - 64)];
        ph = B2hi; pl = B2lo; idx = j;
    } else return;
    unsigned b  = __float_as_uint(v);
    float    hf = __uint_as_float(b & 0xFFFF0000u);
    float    r  = v - hf;
    ph[idx] = (short)(b >> 16);
    pl[idx] = (short)(__float_as_uint(r) >> 16);
}

// ------------- GEMM: out[N,OUT] = [Am|Ax] @ Bcat^T + bias (opt relu) ------
// Per wave: MT m-tiles (16 nodes each) x NT n-tiles (16 outs each), K=128.
// A frags converted+split from fp32 in-register; B pre-split bf16.
template <int MT, int NT, int OUT, int RELU>
__global__ __launch_bounds__(256) void gemm_kernel(
    const float* __restrict__ Am,    // [N,64] aggregated means (K 0..63)
    const float* __restrict__ Ax,    // [N,64] self features    (K 64..127)
    const short* __restrict__ Bhi,   // [OUT,128] bf16 hi
    const short* __restrict__ Blo,   // [OUT,128] bf16 lo
    const float* __restrict__ bias,  // [OUT]
    float*       __restrict__ out)   // [N,OUT]
{
    int wave = (blockIdx.x * 256 + threadIdx.x) >> 6;
    int lane = threadIdx.x & 63;
    int m0   = wave * (MT * 16);
    if (m0 >= N_NODES) return;
    int quad = lane >> 4, l16 = lane & 15;

    f32x4 acc[MT][NT];
    #pragma unroll
    for (int mt = 0; mt < MT; mt++)
        #pragma unroll
        for (int nt = 0; nt < NT; nt++)
            acc[mt][nt] = (f32x4)0.0f;

    #pragma unroll
    for (int half = 0; half < 2; half++) {
        const float* src = half ? Ax : Am;
        #pragma unroll
        for (int sub = 0; sub < 2; sub++) {
            int kf = sub * 32 + quad * 8;            // col in 64-wide source
            int kc = half * 64 + sub * 32 + quad * 8; // col in 128-wide B
            s16x8 ahi[MT], alo[MT];
            #pragma unroll
            for (int mt = 0; mt < MT; mt++) {
                int row = m0 + mt * 16 + l16;
                row = row < N_NODES ? row : N_NODES - 1;
                const float4* p = (const float4*)&src[row * 64 + kf];
                split8(p[0], p[1], ahi[mt], alo[mt]);
            }
            #pragma unroll
            for (int nt = 0; nt < NT; nt++) {
                int n = nt * 16 + l16;
                s16x8 bh = *(const s16x8*)&Bhi[n * 128 + kc];
                s16x8 bl = *(const s16x8*)&Blo[n * 128 + kc];
                #pragma unroll
                for (int mt = 0; mt < MT; mt++) {
                    acc[mt][nt] = __builtin_amdgcn_mfma_f32_16x16x32_bf16(
                        ahi[mt], bh, acc[mt][nt], 0, 0, 0);
                    acc[mt][nt] = __builtin_amdgcn_mfma_f32_16x16x32_bf16(
                        alo[mt], bh, acc[mt][nt], 0, 0, 0);
                    acc[mt][nt] = __builtin_amdgcn_mfma_f32_16x16x32_bf16(
                        ahi[mt], bl, acc[mt][nt], 0, 0, 0);
                }
            }
        }
    }
    // epilogue: D[row=(quad*4+r), col=l16] per 16x16 tile
    #pragma unroll
    for (int nt = 0; nt < NT; nt++) {
        float bv = bias[nt * 16 + l16];
        #pragma unroll
        for (int mt = 0; mt < MT; mt++)
            #pragma unroll
            for (int r = 0; r < 4; r++) {
                int row = m0 + mt * 16 + quad * 4 + r;
                if (row < N_NODES) {
                    float v = acc[mt][nt][r] + bv;
                    if (RELU) v = fmaxf(v, 0.0f);
                    out[row * OUT + nt * 16 + l16] = v;
                }
            }
    }
}

extern "C" void kernel_launch(void* const* d_in, const int* in_sizes, int n_in,
                              void* d_out, int out_size, void* d_ws, size_t ws_size,
                              hipStream_t stream) {
    const float* x   = (const float*)d_in[0];
    const int*   ei1 = (const int*)d_in[1];
    const int*   ei2 = (const int*)d_in[3];
    const float* W1l = (const float*)d_in[5];
    const float* b1  = (const float*)d_in[6];
    const float* W1r = (const float*)d_in[7];
    const float* W2l = (const float*)d_in[8];
    const float* b2  = (const float*)d_in[9];
    const float* W2r = (const float*)d_in[10];
    float* out = (float*)d_out;

    // workspace layout (256B-aligned)
    const size_t off_cnt    = 0;                                   // int[N]
    const size_t off_ovfcnt = 400128;
    const size_t off_ovf    = 400384;                              // int[2*OVF]
    const size_t off_slots  = 433152;                              // int[N*CAP]
    const size_t off_m      = off_slots + (size_t)N_NODES * CAP * 4;
    const size_t off_h      = off_m + (size_t)N_NODES * 64 * 4;
    const size_t off_B1hi   = off_h + (size_t)N_NODES * 64 * 4;
    const size_t off_B1lo   = off_B1hi + 64 * 128 * 2;
    const size_t off_B2hi   = off_B1lo + 64 * 128 * 2;
    const size_t off_B2lo   = off_B2hi + 32 * 128 * 2;

    char* ws = (char*)d_ws;
    int*   cnt     = (int*)(ws + off_cnt);
    int*   ovf_cnt = (int*)(ws + off_ovfcnt);
    int*   ovf     = (int*)(ws + off_ovf);
    int*   slots   = (int*)(ws + off_slots);
    float* m       = (float*)(ws + off_m);
    float* h       = (float*)(ws + off_h);
    short* B1hi    = (short*)(ws + off_B1hi);
    short* B1lo    = (short*)(ws + off_B1lo);
    short* B2hi    = (short*)(ws + off_B2hi);
    short* B2lo    = (short*)(ws + off_B2lo);

    hipMemsetAsync(ws, 0, off_slots, stream);   // cnt + ovf header only

    fill_kernel<<<(2 * E_HALF + 255) / 256, 256, 0, stream>>>(
        ei1, ei2, cnt, slots, ovf_cnt, ovf);
    wsplit_kernel<<<48, 256, 0, stream>>>(
        W1l, W1r, W2l, W2r, B1hi, B1lo, B2hi, B2lo);

    // layer 1: gather-mean(x) -> m ; gemm([m|x] @ [W1l|W1r]^T) -> h (relu)
    gather_mean_kernel<<<N_NODES / 4, 256, 0, stream>>>(x, cnt, slots, m);
    ovf_apply_kernel<<<16, 256, 0, stream>>>(x, cnt, ovf_cnt, ovf, m);
    {   // MT=2 (32 nodes/wave), NT=4 (64 outs): 3125 waves -> 782 blocks
        int waves = (N_NODES + 31) / 32;
        gemm_kernel<2, 4, 64, 1><<<(waves + 3) / 4, 256, 0, stream>>>(
            m, x, B1hi, B1lo, b1, h);
    }

    // layer 2: gather-mean(h) -> m ; gemm([m|h] @ [W2l|W2r]^T) -> out
    gather_mean_kernel<<<N_NODES / 4, 256, 0, stream>>>(h, cnt, slots, m);
    ovf_apply_kernel<<<16, 256, 0, stream>>>(h, cnt, ovf_cnt, ovf, m);
    {   // MT=4 (64 nodes/wave), NT=2 (32 outs): 1563 waves -> 391 blocks
        int waves = (N_NODES + 63) / 64;
        gemm_kernel<4, 2, 32, 0><<<(waves + 3) / 4, 256, 0, stream>>>(
            m, h, B2hi, B2lo, b2, out);
    }
}